// Round 1
// baseline (372.685 us; speedup 1.0000x reference)
//
#include <hip/hip_runtime.h>

typedef unsigned short ushort_t;
typedef unsigned int uint_t;

typedef float f32x4_t __attribute__((ext_vector_type(4)));
typedef short s16x8_t __attribute__((ext_vector_type(8)));

#define NB   256   // B
#define NG   512   // 2*B graphs
#define NPG  24    // nodes per graph
#define NMAXI 32   // N_MAX
#define EPG  200   // edges per graph
#define DD   256   // feature dim
// 1/TEMPERATURE * log2(e) = 10 * 1.4426950408889634
#define L2E_OVER_T 14.426950408889634f

__device__ __forceinline__ ushort_t f2bf(float f) {
    uint_t u = __float_as_uint(f);
    u += 0x7FFFu + ((u >> 16) & 1u);        // round-to-nearest-even
    return (ushort_t)(u >> 16);
}
__device__ __forceinline__ float bfhi(uint_t u) { return __uint_as_float(u & 0xFFFF0000u); }
__device__ __forceinline__ float bflo(uint_t u) { return __uint_as_float(u << 16); }

// ---------------------------------------------------------------------------
// Kernel A: convert W1, W2 to bf16, transposed ([n][k] = B^T layout for MFMA)
// ---------------------------------------------------------------------------
__global__ __launch_bounds__(256) void prep_w(const float* __restrict__ W1,
                                              const float* __restrict__ W2,
                                              ushort_t* __restrict__ W1T,
                                              ushort_t* __restrict__ W2T)
{
    int idx = blockIdx.x * 256 + threadIdx.x;   // 65536 total
    int k = idx >> 8, n = idx & 255;
    W1T[n * 256 + k] = f2bf(W1[idx]);
    W2T[n * 256 + k] = f2bf(W2[idx]);
}

// ---------------------------------------------------------------------------
// Kernel B: fused 2-layer MLP on the 12288 surviving edge rows (rank < 24).
// Y[g*24+e][d] = relu(X @ W1 + b1) @ W2 + b2,  X row = edge_feat[g*200+e].
// MFMA f32_16x16x32_bf16. Block = 256 thr (4 waves), 64 rows per block.
// ---------------------------------------------------------------------------
__global__ __launch_bounds__(256) void mlp_kernel(
    const float* __restrict__ X, const ushort_t* __restrict__ W1T,
    const ushort_t* __restrict__ W2T, const float* __restrict__ b1,
    const float* __restrict__ b2, float* __restrict__ Y)
{
    __shared__ ushort_t sA[64 * 272];   // X tile then (reused) H tile, bf16, stride 272
    const int t = threadIdx.x;
    const int blk = blockIdx.x;
    const int lane = t & 63;
    const int w = t >> 6;               // wave 0..3 -> output cols 64w..64w+63
    const int quad = lane >> 4;
    const int mrow = lane & 15;

    // gather 64 rows of X -> bf16 LDS
    {
        int r = t >> 2;
        int ch = (t & 3) * 64;
        int rho = blk * 64 + r;
        int g = rho / NPG;
        int e = rho - g * NPG;
        const float* src = X + ((size_t)(g * EPG + e)) * DD + ch;
        ushort_t* dst = &sA[r * 272 + ch];
        #pragma unroll
        for (int i = 0; i < 8; ++i) {
            float4 v0 = *(const float4*)(src + i * 8);
            float4 v1 = *(const float4*)(src + i * 8 + 4);
            uint4 pk;
            pk.x = (uint_t)f2bf(v0.x) | ((uint_t)f2bf(v0.y) << 16);
            pk.y = (uint_t)f2bf(v0.z) | ((uint_t)f2bf(v0.w) << 16);
            pk.z = (uint_t)f2bf(v1.x) | ((uint_t)f2bf(v1.y) << 16);
            pk.w = (uint_t)f2bf(v1.z) | ((uint_t)f2bf(v1.w) << 16);
            *(uint4*)(dst + i * 8) = pk;
        }
    }
    __syncthreads();

    // ---- layer 1 ----
    f32x4_t acc[16];
    #pragma unroll
    for (int i = 0; i < 16; ++i) acc[i] = (f32x4_t){0.f, 0.f, 0.f, 0.f};

    #pragma unroll
    for (int k0 = 0; k0 < 256; k0 += 32) {
        s16x8_t a[4], bb[4];
        #pragma unroll
        for (int mt = 0; mt < 4; ++mt)
            a[mt] = *(const s16x8_t*)&sA[(mt * 16 + mrow) * 272 + k0 + quad * 8];
        #pragma unroll
        for (int nt = 0; nt < 4; ++nt)
            bb[nt] = *(const s16x8_t*)(W1T + (size_t)(64 * w + nt * 16 + mrow) * 256 + k0 + quad * 8);
        #pragma unroll
        for (int mt = 0; mt < 4; ++mt) {
            #pragma unroll
            for (int nt = 0; nt < 4; ++nt)
                acc[mt * 4 + nt] = __builtin_amdgcn_mfma_f32_16x16x32_bf16(
                    a[mt], bb[nt], acc[mt * 4 + nt], 0, 0, 0);
        }
    }
    __syncthreads();   // everyone done reading X before H overwrites sA

    // bias + relu -> H (bf16) in sA
    #pragma unroll
    for (int nt = 0; nt < 4; ++nt) {
        int col = 64 * w + nt * 16 + mrow;
        float bias = b1[col];
        #pragma unroll
        for (int mt = 0; mt < 4; ++mt) {
            f32x4_t v = acc[mt * 4 + nt];
            #pragma unroll
            for (int reg = 0; reg < 4; ++reg) {
                int row = mt * 16 + quad * 4 + reg;   // C layout: row=quad*4+reg, col=lane&15
                sA[row * 272 + col] = f2bf(fmaxf(v[reg] + bias, 0.f));
            }
        }
    }
    __syncthreads();

    // ---- layer 2 ----
    #pragma unroll
    for (int i = 0; i < 16; ++i) acc[i] = (f32x4_t){0.f, 0.f, 0.f, 0.f};

    #pragma unroll
    for (int k0 = 0; k0 < 256; k0 += 32) {
        s16x8_t a[4], bb[4];
        #pragma unroll
        for (int mt = 0; mt < 4; ++mt)
            a[mt] = *(const s16x8_t*)&sA[(mt * 16 + mrow) * 272 + k0 + quad * 8];
        #pragma unroll
        for (int nt = 0; nt < 4; ++nt)
            bb[nt] = *(const s16x8_t*)(W2T + (size_t)(64 * w + nt * 16 + mrow) * 256 + k0 + quad * 8);
        #pragma unroll
        for (int mt = 0; mt < 4; ++mt) {
            #pragma unroll
            for (int nt = 0; nt < 4; ++nt)
                acc[mt * 4 + nt] = __builtin_amdgcn_mfma_f32_16x16x32_bf16(
                    a[mt], bb[nt], acc[mt * 4 + nt], 0, 0, 0);
        }
    }

    #pragma unroll
    for (int nt = 0; nt < 4; ++nt) {
        int col = 64 * w + nt * 16 + mrow;
        float bias = b2[col];
        #pragma unroll
        for (int mt = 0; mt < 4; ++mt) {
            f32x4_t v = acc[mt * 4 + nt];
            #pragma unroll
            for (int reg = 0; reg < 4; ++reg) {
                int row = blk * 64 + mt * 16 + quad * 4 + reg;
                Y[(size_t)row * 256 + col] = v[reg] + bias;
            }
        }
    }
}

// ---------------------------------------------------------------------------
// Kernel C: per-b fused  K-build -> 20x linear-domain Sinkhorn -> score.
// Block = 1024 thr; thread (r = t>>2, q = t&3) owns K[r][64q..64q+63] in VGPRs.
// K^T (bf16) lives in workspace; per-block slice 128 KB -> L2-resident.
// ---------------------------------------------------------------------------
__global__ __launch_bounds__(1024) void sink_kernel(
    const float* __restrict__ Tplan, const int* __restrict__ from_idx,
    const int* __restrict__ to_idx, const int* __restrict__ qsz,
    const int* __restrict__ csz, const float* __restrict__ qcf,
    ushort_t* __restrict__ Ktg, float* __restrict__ out)
{
    const int b = blockIdx.x;
    const int t = threadIdx.x;
    const int r = t >> 2;   // row (row step) / col j (col step)
    const int q = t & 3;    // 64-wide chunk

    __shared__ float Tl[33 * 33];                  // padded transport plan
    __shared__ int fq[256], tqv[256], fc[256], tcv[256];
    __shared__ float ru[256], rv[256];             // 1/U, 1/V
    __shared__ float plan_s[256 * 25];             // plan[:, :24], stride 25
    __shared__ float cf_s[24 * 264];               // c_feat rows <24, stride 264
    __shared__ float wsum[16];

    // --- phase 1: zero T border, load edge indices, init rv ---
    for (int i = t; i < 33 * 33; i += 1024) Tl[i] = 0.f;
    if (t < 256) {
        rv[t] = 1.0f;
        int gq = 2 * b, gc = 2 * b + 1;
        int a = NMAXI, bb = NMAXI, c = NMAXI, d = NMAXI;
        if (t < EPG) {
            a  = from_idx[gq * EPG + t] - gq * NPG;
            bb = to_idx  [gq * EPG + t] - gq * NPG;
            c  = from_idx[gc * EPG + t] - gc * NPG;
            d  = to_idx  [gc * EPG + t] - gc * NPG;
        }
        fq[t] = a; tqv[t] = bb; fc[t] = c; tcv[t] = d;
    }
    __syncthreads();
    {   // fill T interior (row/col 32 stay zero)
        int i = t >> 5, j = t & 31;
        Tl[i * 33 + j] = Tplan[((size_t)b << 10) + t];
    }
    __syncthreads();

    // --- build K (f32, registers, row-major) ---
    float K[64];
    {
        const float* T1 = &Tl[fq[r] * 33];
        const float* T2 = &Tl[tqv[r] * 33];
        #pragma unroll
        for (int o = 0; o < 64; ++o) {
            int cidx = q * 64 + o;
            int f_ = fc[cidx], t_ = tcv[cidx];
            float la = T1[f_] * T2[t_] + T1[t_] * T2[f_];   // straight + cross
            K[o] = exp2f(la * L2E_OVER_T);
        }
    }
    // --- build K^T (bf16) -> workspace: thread = (col j=r, rows q*64..+63) ---
    {
        int j = r;
        int f_ = fc[j], t_ = tcv[j];
        uint4* dst = (uint4*)(Ktg + ((size_t)b * 256 + j) * 256 + q * 64);
        #pragma unroll
        for (int oo = 0; oo < 8; ++oo) {
            uint_t u[4];
            #pragma unroll
            for (int p2 = 0; p2 < 4; ++p2) {
                int i0 = q * 64 + oo * 8 + p2 * 2;
                const float* A1 = &Tl[fq[i0] * 33];
                const float* A2 = &Tl[tqv[i0] * 33];
                float la0 = A1[f_] * A2[t_] + A1[t_] * A2[f_];
                const float* B1 = &Tl[fq[i0 + 1] * 33];
                const float* B2 = &Tl[tqv[i0 + 1] * 33];
                float la1 = B1[f_] * B2[t_] + B1[t_] * B2[f_];
                u[p2] = (uint_t)f2bf(exp2f(la0 * L2E_OVER_T))
                      | ((uint_t)f2bf(exp2f(la1 * L2E_OVER_T)) << 16);
            }
            uint4 pk; pk.x = u[0]; pk.y = u[1]; pk.z = u[2]; pk.w = u[3];
            dst[oo] = pk;
        }
    }
    __syncthreads();   // drains vmcnt -> K^T visible via L2 to whole block

    // --- 20 Sinkhorn iterations, linear domain ---
    const float4* rv4 = (const float4*)&rv[q * 64];
    const float4* ru4 = (const float4*)&ru[q * 64];
    const uint4* kt4 = (const uint4*)(Ktg + ((size_t)b * 256 + r) * 256 + q * 64);

    for (int it = 0; it < 20; ++it) {
        // row step: U_r = sum_j K[r][j] * rv[j]
        float a0 = 0.f, a1 = 0.f, a2 = 0.f, a3 = 0.f;
        #pragma unroll
        for (int c4 = 0; c4 < 16; ++c4) {
            float4 v = rv4[c4];
            a0 += K[c4 * 4 + 0] * v.x;
            a1 += K[c4 * 4 + 1] * v.y;
            a2 += K[c4 * 4 + 2] * v.z;
            a3 += K[c4 * 4 + 3] * v.w;
        }
        float s = (a0 + a1) + (a2 + a3);
        s += __shfl_xor(s, 1);
        s += __shfl_xor(s, 2);
        if (q == 0) ru[r] = 1.0f / s;
        __syncthreads();
        // col step: V_j = sum_i K[i][j] * ru[i]   (j = r, via K^T from L2)
        a0 = a1 = a2 = a3 = 0.f;
        #pragma unroll
        for (int c8 = 0; c8 < 8; ++c8) {
            uint4 kv = kt4[c8];
            float4 u0 = ru4[c8 * 2 + 0];
            float4 u1 = ru4[c8 * 2 + 1];
            a0 += bflo(kv.x) * u0.x; a1 += bfhi(kv.x) * u0.y;
            a2 += bflo(kv.y) * u0.z; a3 += bfhi(kv.y) * u0.w;
            a0 += bflo(kv.z) * u1.x; a1 += bfhi(kv.z) * u1.y;
            a2 += bflo(kv.w) * u1.z; a3 += bfhi(kv.w) * u1.w;
        }
        s = (a0 + a1) + (a2 + a3);
        s += __shfl_xor(s, 1);
        s += __shfl_xor(s, 2);
        if (q == 0) rv[r] = 1.0f / s;
        __syncthreads();
    }

    // --- score: pc = plan[:, :nc] @ cf ; ssum = sum relu(qf - pc) ---
    int nq = qsz[b]; if (nq > 24) nq = 24;
    int nc = csz[b]; if (nc > 24) nc = 24;

    if (q == 0) {   // plan[r][j] = K[r][j] * ru[r] * rv[j], j < 24
        float rr = ru[r];
        #pragma unroll
        for (int j = 0; j < 24; ++j)
            plan_s[r * 25 + j] = K[j] * rr * rv[j];
    }
    if (t < 768) {  // load cf rows (corpus graph 2b+1) to LDS
        int j = t >> 5;
        int c0 = (t & 31) * 8;
        const float* src = qcf + ((size_t)(2 * b + 1) * 24 + j) * 256 + c0;
        float4 v0 = *(const float4*)(src);
        float4 v1 = *(const float4*)(src + 4);
        *(float4*)&cf_s[j * 264 + c0] = v0;
        *(float4*)&cf_s[j * 264 + c0 + 4] = v1;
    }
    __syncthreads();

    float ssum = 0.f;
    const float* qrow = qcf + ((size_t)(2 * b) * 24 + r) * 256;
    #pragma unroll
    for (int h = 0; h < 2; ++h) {
        float pc[32];
        #pragma unroll
        for (int i = 0; i < 32; ++i) pc[i] = 0.f;
        for (int j = 0; j < nc; ++j) {
            float p = plan_s[r * 25 + j];
            const float4* cfp = (const float4*)&cf_s[j * 264 + q * 64 + h * 32];
            #pragma unroll
            for (int k = 0; k < 8; ++k) {
                float4 cv = cfp[k];
                pc[k * 4 + 0] += p * cv.x;
                pc[k * 4 + 1] += p * cv.y;
                pc[k * 4 + 2] += p * cv.z;
                pc[k * 4 + 3] += p * cv.w;
            }
        }
        if (r < nq) {
            const float4* qp = (const float4*)(qrow + q * 64 + h * 32);
            #pragma unroll
            for (int k = 0; k < 8; ++k) {
                float4 qv = qp[k];
                ssum += fmaxf(qv.x - pc[k * 4 + 0], 0.f);
                ssum += fmaxf(qv.y - pc[k * 4 + 1], 0.f);
                ssum += fmaxf(qv.z - pc[k * 4 + 2], 0.f);
                ssum += fmaxf(qv.w - pc[k * 4 + 3], 0.f);
            }
        } else {
            #pragma unroll
            for (int k = 0; k < 32; ++k) ssum += fmaxf(-pc[k], 0.f);
        }
    }
    ssum += __shfl_xor(ssum, 1);
    ssum += __shfl_xor(ssum, 2);
    ssum += __shfl_xor(ssum, 4);
    ssum += __shfl_xor(ssum, 8);
    ssum += __shfl_xor(ssum, 16);
    ssum += __shfl_xor(ssum, 32);
    if ((t & 63) == 0) wsum[t >> 6] = ssum;
    __syncthreads();
    if (t == 0) {
        float s = 0.f;
        #pragma unroll
        for (int i = 0; i < 16; ++i) s += wsum[i];
        out[b] = -s;
    }
}

// ---------------------------------------------------------------------------
extern "C" void kernel_launch(void* const* d_in, const int* in_sizes, int n_in,
                              void* d_out, int out_size, void* d_ws, size_t ws_size,
                              hipStream_t stream)
{
    const float* edge_feat = (const float*)d_in[0];
    const float* tplan     = (const float*)d_in[1];
    const float* W1        = (const float*)d_in[2];
    const float* b1        = (const float*)d_in[3];
    const float* W2        = (const float*)d_in[4];
    const float* b2        = (const float*)d_in[5];
    const int*   from_idx  = (const int*)d_in[6];
    const int*   to_idx    = (const int*)d_in[7];
    const int*   qsz       = (const int*)d_in[9];
    const int*   csz       = (const int*)d_in[10];
    float* out = (float*)d_out;

    // workspace layout (total ~44.3 MB):
    //   [0, 128K)          W1T bf16
    //   [128K, 256K)       W2T bf16
    //   [256K, 256K+12MB)  qcf f32 [512][24][256]
    //   [+, +32MB)         Ktg bf16 [256][256][256]
    char* ws = (char*)d_ws;
    ushort_t* W1T = (ushort_t*)ws;
    ushort_t* W2T = W1T + 65536;
    float* qcf = (float*)(ws + 262144);
    ushort_t* Ktg = (ushort_t*)(ws + 262144 + 12582912);

    prep_w<<<256, 256, 0, stream>>>(W1, W2, W1T, W2T);
    mlp_kernel<<<192, 256, 0, stream>>>(edge_feat, W1T, W2T, b1, b2, qcf);
    sink_kernel<<<256, 1024, 0, stream>>>(tplan, from_idx, to_idx, qsz, csz, qcf, Ktg, out);
}

// Round 2
// 332.697 us; speedup vs baseline: 1.1202x; 1.1202x over previous
//
#include <hip/hip_runtime.h>

typedef unsigned short ushort_t;
typedef unsigned int uint_t;

typedef float f32x4_t __attribute__((ext_vector_type(4)));
typedef short s16x8_t __attribute__((ext_vector_type(8)));

#define NB   256   // B
#define NG   512   // 2*B graphs
#define NPG  24    // nodes per graph
#define NMAXI 32   // N_MAX
#define EPG  200   // edges per graph
#define DD   256   // feature dim
// 1/TEMPERATURE * log2(e) = 10 * 1.4426950408889634
#define L2E_OVER_T 14.426950408889634f

__device__ __forceinline__ ushort_t f2bf(float f) {
    uint_t u = __float_as_uint(f);
    u += 0x7FFFu + ((u >> 16) & 1u);        // round-to-nearest-even
    return (ushort_t)(u >> 16);
}
__device__ __forceinline__ float bfhi(uint_t u) { return __uint_as_float(u & 0xFFFF0000u); }
__device__ __forceinline__ float bflo(uint_t u) { return __uint_as_float(u << 16); }

__device__ __forceinline__ float frcp(float x) {
#if __has_builtin(__builtin_amdgcn_rcpf)
    return __builtin_amdgcn_rcpf(x);   // v_rcp_f32, ~1 ulp — Sinkhorn self-corrects
#else
    return 1.0f / x;
#endif
}

// ---------------------------------------------------------------------------
// Kernel A: convert W1, W2 to bf16, transposed ([n][k] = B^T layout for MFMA)
// ---------------------------------------------------------------------------
__global__ __launch_bounds__(256) void prep_w(const float* __restrict__ W1,
                                              const float* __restrict__ W2,
                                              ushort_t* __restrict__ W1T,
                                              ushort_t* __restrict__ W2T)
{
    int idx = blockIdx.x * 256 + threadIdx.x;   // 65536 total
    int k = idx >> 8, n = idx & 255;
    W1T[n * 256 + k] = f2bf(W1[idx]);
    W2T[n * 256 + k] = f2bf(W2[idx]);
}

// ---------------------------------------------------------------------------
// Kernel B: fused 2-layer MLP on the 12288 surviving edge rows (rank < 24).
// ---------------------------------------------------------------------------
__global__ __launch_bounds__(256) void mlp_kernel(
    const float* __restrict__ X, const ushort_t* __restrict__ W1T,
    const ushort_t* __restrict__ W2T, const float* __restrict__ b1,
    const float* __restrict__ b2, float* __restrict__ Y)
{
    __shared__ ushort_t sA[64 * 272];
    const int t = threadIdx.x;
    const int blk = blockIdx.x;
    const int lane = t & 63;
    const int w = t >> 6;
    const int quad = lane >> 4;
    const int mrow = lane & 15;

    {
        int r = t >> 2;
        int ch = (t & 3) * 64;
        int rho = blk * 64 + r;
        int g = rho / NPG;
        int e = rho - g * NPG;
        const float* src = X + ((size_t)(g * EPG + e)) * DD + ch;
        ushort_t* dst = &sA[r * 272 + ch];
        #pragma unroll
        for (int i = 0; i < 8; ++i) {
            float4 v0 = *(const float4*)(src + i * 8);
            float4 v1 = *(const float4*)(src + i * 8 + 4);
            uint4 pk;
            pk.x = (uint_t)f2bf(v0.x) | ((uint_t)f2bf(v0.y) << 16);
            pk.y = (uint_t)f2bf(v0.z) | ((uint_t)f2bf(v0.w) << 16);
            pk.z = (uint_t)f2bf(v1.x) | ((uint_t)f2bf(v1.y) << 16);
            pk.w = (uint_t)f2bf(v1.z) | ((uint_t)f2bf(v1.w) << 16);
            *(uint4*)(dst + i * 8) = pk;
        }
    }
    __syncthreads();

    f32x4_t acc[16];
    #pragma unroll
    for (int i = 0; i < 16; ++i) acc[i] = (f32x4_t){0.f, 0.f, 0.f, 0.f};

    #pragma unroll
    for (int k0 = 0; k0 < 256; k0 += 32) {
        s16x8_t a[4], bb[4];
        #pragma unroll
        for (int mt = 0; mt < 4; ++mt)
            a[mt] = *(const s16x8_t*)&sA[(mt * 16 + mrow) * 272 + k0 + quad * 8];
        #pragma unroll
        for (int nt = 0; nt < 4; ++nt)
            bb[nt] = *(const s16x8_t*)(W1T + (size_t)(64 * w + nt * 16 + mrow) * 256 + k0 + quad * 8);
        #pragma unroll
        for (int mt = 0; mt < 4; ++mt) {
            #pragma unroll
            for (int nt = 0; nt < 4; ++nt)
                acc[mt * 4 + nt] = __builtin_amdgcn_mfma_f32_16x16x32_bf16(
                    a[mt], bb[nt], acc[mt * 4 + nt], 0, 0, 0);
        }
    }
    __syncthreads();

    #pragma unroll
    for (int nt = 0; nt < 4; ++nt) {
        int col = 64 * w + nt * 16 + mrow;
        float bias = b1[col];
        #pragma unroll
        for (int mt = 0; mt < 4; ++mt) {
            f32x4_t v = acc[mt * 4 + nt];
            #pragma unroll
            for (int reg = 0; reg < 4; ++reg) {
                int row = mt * 16 + quad * 4 + reg;
                sA[row * 272 + col] = f2bf(fmaxf(v[reg] + bias, 0.f));
            }
        }
    }
    __syncthreads();

    #pragma unroll
    for (int i = 0; i < 16; ++i) acc[i] = (f32x4_t){0.f, 0.f, 0.f, 0.f};

    #pragma unroll
    for (int k0 = 0; k0 < 256; k0 += 32) {
        s16x8_t a[4], bb[4];
        #pragma unroll
        for (int mt = 0; mt < 4; ++mt)
            a[mt] = *(const s16x8_t*)&sA[(mt * 16 + mrow) * 272 + k0 + quad * 8];
        #pragma unroll
        for (int nt = 0; nt < 4; ++nt)
            bb[nt] = *(const s16x8_t*)(W2T + (size_t)(64 * w + nt * 16 + mrow) * 256 + k0 + quad * 8);
        #pragma unroll
        for (int mt = 0; mt < 4; ++mt) {
            #pragma unroll
            for (int nt = 0; nt < 4; ++nt)
                acc[mt * 4 + nt] = __builtin_amdgcn_mfma_f32_16x16x32_bf16(
                    a[mt], bb[nt], acc[mt * 4 + nt], 0, 0, 0);
        }
    }

    #pragma unroll
    for (int nt = 0; nt < 4; ++nt) {
        int col = 64 * w + nt * 16 + mrow;
        float bias = b2[col];
        #pragma unroll
        for (int mt = 0; mt < 4; ++mt) {
            f32x4_t v = acc[mt * 4 + nt];
            #pragma unroll
            for (int reg = 0; reg < 4; ++reg) {
                int row = blk * 64 + mt * 16 + quad * 4 + reg;
                Y[(size_t)row * 256 + col] = v[reg] + bias;
            }
        }
    }
}

// ---------------------------------------------------------------------------
// Kernel C: per-b fused K-build -> 20x linear-domain Sinkhorn -> score.
// Thread (r = t>>2, q = t&3) owns:
//   K  row chunk  K[r][64q..64q+63]   as 64 f32 registers  (row step, plan)
//   K^T col chunk K[64q..64q+63][r]   as 32 packed-bf16 uint registers (col step)
// NO global K traffic at all. Shared arrays phase-overlaid in 56 KB.
// ---------------------------------------------------------------------------
__global__ __launch_bounds__(1024) void sink_kernel(
    const float* __restrict__ Tplan, const int* __restrict__ from_idx,
    const int* __restrict__ to_idx, const int* __restrict__ qsz,
    const int* __restrict__ csz, const float* __restrict__ qcf,
    float* __restrict__ out)
{
    const int b = blockIdx.x;
    const int t = threadIdx.x;
    const int r = t >> 2;   // row (row step) / col j (col step)
    const int q = t & 3;    // 64-wide chunk

    // overlay region: build {Tl 4368 | fq/tq/fc/tc 4x1024} vs score {plan_s 25600 | cf_s 30720}
    __shared__ __align__(16) char ovl[56320];
    __shared__ float ru[256], rv[256];
    __shared__ float wsum[16];

    float* Tl = (float*)ovl;                 // 33*33 floats, padded region
    int* fq = (int*)(ovl + 4368);
    int* tq = (int*)(ovl + 5392);
    int* fc = (int*)(ovl + 6416);
    int* tc = (int*)(ovl + 7440);
    float* plan_s = (float*)ovl;             // [256][25] f32
    float* cf_s   = (float*)(ovl + 25600);   // [24][16 chunks * 20] f32, swizzled

    // --- phase 1: zero T border, load edge indices, init rv ---
    for (int i = t; i < 33 * 33; i += 1024) Tl[i] = 0.f;
    if (t < 256) {
        rv[t] = 1.0f;
        int gq = 2 * b, gc = 2 * b + 1;
        int a = NMAXI, bb = NMAXI, c = NMAXI, d = NMAXI;
        if (t < EPG) {
            a  = from_idx[gq * EPG + t] - gq * NPG;
            bb = to_idx  [gq * EPG + t] - gq * NPG;
            c  = from_idx[gc * EPG + t] - gc * NPG;
            d  = to_idx  [gc * EPG + t] - gc * NPG;
        }
        fq[t] = a; tq[t] = bb; fc[t] = c; tc[t] = d;
    }
    __syncthreads();
    {   // fill T interior (row/col 32 stay zero)
        int i = t >> 5, j = t & 31;
        Tl[i * 33 + j] = Tplan[((size_t)b << 10) + t];
    }
    __syncthreads();

    // --- build K row chunk (f32 registers) ---
    float K[64];
    {
        const float* T1 = &Tl[fq[r] * 33];
        const float* T2 = &Tl[tq[r] * 33];
        #pragma unroll
        for (int o = 0; o < 64; ++o) {
            int cidx = q * 64 + o;
            int f_ = fc[cidx], t_ = tc[cidx];
            float la = T1[f_] * T2[t_] + T1[t_] * T2[f_];   // straight + cross
            K[o] = exp2f(la * L2E_OVER_T);
        }
    }
    // --- build K^T col chunk (packed bf16 in registers) ---
    uint_t KTp[32];
    {
        int j = r;
        int f_ = fc[j], t_ = tc[j];
        #pragma unroll
        for (int oo = 0; oo < 8; ++oo) {
            #pragma unroll
            for (int p2 = 0; p2 < 4; ++p2) {
                int i0 = q * 64 + oo * 8 + p2 * 2;
                const float* A1 = &Tl[fq[i0] * 33];
                const float* A2 = &Tl[tq[i0] * 33];
                float la0 = A1[f_] * A2[t_] + A1[t_] * A2[f_];
                const float* B1 = &Tl[fq[i0 + 1] * 33];
                const float* B2 = &Tl[tq[i0 + 1] * 33];
                float la1 = B1[f_] * B2[t_] + B1[t_] * B2[f_];
                KTp[oo * 4 + p2] = (uint_t)f2bf(exp2f(la0 * L2E_OVER_T))
                                 | ((uint_t)f2bf(exp2f(la1 * L2E_OVER_T)) << 16);
            }
        }
    }

    // --- 20 Sinkhorn iterations, linear domain, all-register K ---
    const float4* rv4 = (const float4*)&rv[q * 64];
    const float4* ru4 = (const float4*)&ru[q * 64];

    for (int it = 0; it < 20; ++it) {
        // row step: U_r = sum_j K[r][j] * rv[j]
        float a0 = 0.f, a1 = 0.f, a2 = 0.f, a3 = 0.f;
        #pragma unroll
        for (int c4 = 0; c4 < 16; ++c4) {
            float4 v = rv4[c4];
            a0 += K[c4 * 4 + 0] * v.x;
            a1 += K[c4 * 4 + 1] * v.y;
            a2 += K[c4 * 4 + 2] * v.z;
            a3 += K[c4 * 4 + 3] * v.w;
        }
        float s = (a0 + a1) + (a2 + a3);
        s += __shfl_xor(s, 1);
        s += __shfl_xor(s, 2);
        if (q == 0) ru[r] = frcp(s);
        __syncthreads();
        // col step: V_j = sum_i K[i][j] * ru[i]   (j = r, K^T from registers)
        a0 = a1 = a2 = a3 = 0.f;
        #pragma unroll
        for (int c8 = 0; c8 < 8; ++c8) {
            uint_t k0 = KTp[c8 * 4 + 0], k1 = KTp[c8 * 4 + 1];
            uint_t k2 = KTp[c8 * 4 + 2], k3 = KTp[c8 * 4 + 3];
            float4 u0 = ru4[c8 * 2 + 0];
            float4 u1 = ru4[c8 * 2 + 1];
            a0 += bflo(k0) * u0.x; a1 += bfhi(k0) * u0.y;
            a2 += bflo(k1) * u0.z; a3 += bfhi(k1) * u0.w;
            a0 += bflo(k2) * u1.x; a1 += bfhi(k2) * u1.y;
            a2 += bflo(k3) * u1.z; a3 += bfhi(k3) * u1.w;
        }
        s = (a0 + a1) + (a2 + a3);
        s += __shfl_xor(s, 1);
        s += __shfl_xor(s, 2);
        if (q == 0) rv[r] = frcp(s);
        __syncthreads();
    }

    // --- score phase ---
    int nq = qsz[b]; if (nq > 24) nq = 24;
    int nc = csz[b]; if (nc > 24) nc = 24;

    if (q == 0) {   // plan[r][j] = K[r][j] * ru[r] * rv[j], j < 24 (q==0 owns j<64)
        float rr = ru[r];
        #pragma unroll
        for (int j = 0; j < 24; ++j)
            plan_s[r * 25 + j] = K[j] * rr * rv[j];
    }
    if (t < 768) {  // cf rows (<24) -> swizzled LDS chunks of 16 floats @ stride 20
        int j = t >> 5, inner = t & 31;
        int c = inner * 8;
        const float* src = qcf + ((size_t)(2 * b + 1) * 24 + j) * 256 + c;
        float4 v0 = *(const float4*)(src);
        float4 v1 = *(const float4*)(src + 4);
        float* dst = cf_s + j * 320 + (c >> 4) * 20 + (c & 15);
        *(float4*)dst = v0;
        *(float4*)(dst + 4) = v1;
    }
    __syncthreads();

    // thread = 4 rows x 16 cols
    const int rg = t >> 4;        // 0..63
    const int r0 = rg * 4;        // rows r0..r0+3
    const int m  = t & 15;        // cols m*16 .. m*16+15

    float pc[64];
    #pragma unroll
    for (int i = 0; i < 64; ++i) pc[i] = 0.f;

    for (int j = 0; j < nc; ++j) {
        float p0 = plan_s[(r0 + 0) * 25 + j];
        float p1 = plan_s[(r0 + 1) * 25 + j];
        float p2 = plan_s[(r0 + 2) * 25 + j];
        float p3 = plan_s[(r0 + 3) * 25 + j];
        const float4* cfp = (const float4*)(cf_s + j * 320 + m * 20);
        #pragma unroll
        for (int k = 0; k < 4; ++k) {
            float4 cv = cfp[k];
            pc[ 0 + k * 4 + 0] += p0 * cv.x; pc[ 0 + k * 4 + 1] += p0 * cv.y;
            pc[ 0 + k * 4 + 2] += p0 * cv.z; pc[ 0 + k * 4 + 3] += p0 * cv.w;
            pc[16 + k * 4 + 0] += p1 * cv.x; pc[16 + k * 4 + 1] += p1 * cv.y;
            pc[16 + k * 4 + 2] += p1 * cv.z; pc[16 + k * 4 + 3] += p1 * cv.w;
            pc[32 + k * 4 + 0] += p2 * cv.x; pc[32 + k * 4 + 1] += p2 * cv.y;
            pc[32 + k * 4 + 2] += p2 * cv.z; pc[32 + k * 4 + 3] += p2 * cv.w;
            pc[48 + k * 4 + 0] += p3 * cv.x; pc[48 + k * 4 + 1] += p3 * cv.y;
            pc[48 + k * 4 + 2] += p3 * cv.z; pc[48 + k * 4 + 3] += p3 * cv.w;
        }
    }

    float ssum = 0.f;
    const float* qbase = qcf + (size_t)(2 * b) * 24 * 256;
    #pragma unroll
    for (int i = 0; i < 4; ++i) {
        int row = r0 + i;
        if (row < nq) {
            const float4* qp = (const float4*)(qbase + (size_t)row * 256 + m * 16);
            #pragma unroll
            for (int k = 0; k < 4; ++k) {
                float4 qv = qp[k];
                ssum += fmaxf(qv.x - pc[i * 16 + k * 4 + 0], 0.f);
                ssum += fmaxf(qv.y - pc[i * 16 + k * 4 + 1], 0.f);
                ssum += fmaxf(qv.z - pc[i * 16 + k * 4 + 2], 0.f);
                ssum += fmaxf(qv.w - pc[i * 16 + k * 4 + 3], 0.f);
            }
        } else {
            #pragma unroll
            for (int k = 0; k < 16; ++k) ssum += fmaxf(-pc[i * 16 + k], 0.f);
        }
    }
    ssum += __shfl_xor(ssum, 1);
    ssum += __shfl_xor(ssum, 2);
    ssum += __shfl_xor(ssum, 4);
    ssum += __shfl_xor(ssum, 8);
    ssum += __shfl_xor(ssum, 16);
    ssum += __shfl_xor(ssum, 32);
    if ((t & 63) == 0) wsum[t >> 6] = ssum;
    __syncthreads();
    if (t == 0) {
        float s = 0.f;
        #pragma unroll
        for (int i = 0; i < 16; ++i) s += wsum[i];
        out[b] = -s;
    }
}

// ---------------------------------------------------------------------------
extern "C" void kernel_launch(void* const* d_in, const int* in_sizes, int n_in,
                              void* d_out, int out_size, void* d_ws, size_t ws_size,
                              hipStream_t stream)
{
    const float* edge_feat = (const float*)d_in[0];
    const float* tplan     = (const float*)d_in[1];
    const float* W1        = (const float*)d_in[2];
    const float* b1        = (const float*)d_in[3];
    const float* W2        = (const float*)d_in[4];
    const float* b2        = (const float*)d_in[5];
    const int*   from_idx  = (const int*)d_in[6];
    const int*   to_idx    = (const int*)d_in[7];
    const int*   qsz       = (const int*)d_in[9];
    const int*   csz       = (const int*)d_in[10];
    float* out = (float*)d_out;

    // workspace: [0,128K) W1T bf16 | [128K,256K) W2T bf16 | [256K,+12.6MB) qcf f32
    char* ws = (char*)d_ws;
    ushort_t* W1T = (ushort_t*)ws;
    ushort_t* W2T = W1T + 65536;
    float* qcf = (float*)(ws + 262144);

    prep_w<<<256, 256, 0, stream>>>(W1, W2, W1T, W2T);
    mlp_kernel<<<192, 256, 0, stream>>>(edge_feat, W1T, W2T, b1, b2, qcf);
    sink_kernel<<<256, 1024, 0, stream>>>(tplan, from_idx, to_idx, qsz, csz, qcf, out);
}

// Round 3
// 286.949 us; speedup vs baseline: 1.2988x; 1.1594x over previous
//
#include <hip/hip_runtime.h>

typedef unsigned short ushort_t;
typedef unsigned int uint_t;

typedef float f32x4_t __attribute__((ext_vector_type(4)));
typedef short s16x8_t __attribute__((ext_vector_type(8)));

#define NB   256   // B
#define NG   512   // 2*B graphs
#define NPG  24    // nodes per graph
#define NMAXI 32   // N_MAX
#define EPG  200   // edges per graph
#define DD   256   // feature dim
// 1/TEMPERATURE * log2(e) = 10 * 1.4426950408889634
#define L2E_OVER_T 14.426950408889634f

// padded index for ru/rv: 64-float chunks at stride 68 (4-bank shift per chunk)
#define PADIDX(i) ((((i) >> 6) * 68) + ((i) & 63))

__device__ __forceinline__ ushort_t f2bf(float f) {
    uint_t u = __float_as_uint(f);
    u += 0x7FFFu + ((u >> 16) & 1u);        // round-to-nearest-even
    return (ushort_t)(u >> 16);
}
__device__ __forceinline__ float bfhi(uint_t u) { return __uint_as_float(u & 0xFFFF0000u); }
__device__ __forceinline__ float bflo(uint_t u) { return __uint_as_float(u << 16); }

__device__ __forceinline__ float frcp(float x) {
#if __has_builtin(__builtin_amdgcn_rcpf)
    return __builtin_amdgcn_rcpf(x);
#else
    return 1.0f / x;
#endif
}

// ---------------------------------------------------------------------------
// Kernel A: W1,W2 -> bf16 transposed ([n][k]), via LDS transpose.
// 64 blocks x 256 thr; block handles k-rows [4*blk, 4*blk+4) of both matrices.
// Coalesced f32 loads; 8B-contiguous packed stores per thread.
// ---------------------------------------------------------------------------
__global__ __launch_bounds__(256) void prep_w(const float* __restrict__ W1,
                                              const float* __restrict__ W2,
                                              ushort_t* __restrict__ W1T,
                                              ushort_t* __restrict__ W2T)
{
    __shared__ float tile[2][4 * 256];
    const int t = threadIdx.x;
    const int k0 = blockIdx.x * 4;
    #pragma unroll
    for (int i = t; i < 4 * 256; i += 256) {
        tile[0][i] = W1[k0 * 256 + i];
        tile[1][i] = W2[k0 * 256 + i];
    }
    __syncthreads();
    const int n = t;
    #pragma unroll
    for (int m = 0; m < 2; ++m) {
        uint_t p0 = (uint_t)f2bf(tile[m][0 * 256 + n]) | ((uint_t)f2bf(tile[m][1 * 256 + n]) << 16);
        uint_t p1 = (uint_t)f2bf(tile[m][2 * 256 + n]) | ((uint_t)f2bf(tile[m][3 * 256 + n]) << 16);
        ushort_t* dst = (m ? W2T : W1T) + n * 256 + k0;
        uint2 pk; pk.x = p0; pk.y = p1;
        *(uint2*)dst = pk;
    }
}

// ---------------------------------------------------------------------------
// Kernel B: fused 2-layer MLP on the 12288 surviving edge rows (rank < 24).
// ---------------------------------------------------------------------------
__global__ __launch_bounds__(256) void mlp_kernel(
    const float* __restrict__ X, const ushort_t* __restrict__ W1T,
    const ushort_t* __restrict__ W2T, const float* __restrict__ b1,
    const float* __restrict__ b2, float* __restrict__ Y)
{
    __shared__ ushort_t sA[64 * 272];
    const int t = threadIdx.x;
    const int blk = blockIdx.x;
    const int lane = t & 63;
    const int w = t >> 6;
    const int quad = lane >> 4;
    const int mrow = lane & 15;

    {
        int r = t >> 2;
        int ch = (t & 3) * 64;
        int rho = blk * 64 + r;
        int g = rho / NPG;
        int e = rho - g * NPG;
        const float* src = X + ((size_t)(g * EPG + e)) * DD + ch;
        ushort_t* dst = &sA[r * 272 + ch];
        #pragma unroll
        for (int i = 0; i < 8; ++i) {
            float4 v0 = *(const float4*)(src + i * 8);
            float4 v1 = *(const float4*)(src + i * 8 + 4);
            uint4 pk;
            pk.x = (uint_t)f2bf(v0.x) | ((uint_t)f2bf(v0.y) << 16);
            pk.y = (uint_t)f2bf(v0.z) | ((uint_t)f2bf(v0.w) << 16);
            pk.z = (uint_t)f2bf(v1.x) | ((uint_t)f2bf(v1.y) << 16);
            pk.w = (uint_t)f2bf(v1.z) | ((uint_t)f2bf(v1.w) << 16);
            *(uint4*)(dst + i * 8) = pk;
        }
    }
    __syncthreads();

    f32x4_t acc[16];
    #pragma unroll
    for (int i = 0; i < 16; ++i) acc[i] = (f32x4_t){0.f, 0.f, 0.f, 0.f};

    #pragma unroll
    for (int k0 = 0; k0 < 256; k0 += 32) {
        s16x8_t a[4], bb[4];
        #pragma unroll
        for (int mt = 0; mt < 4; ++mt)
            a[mt] = *(const s16x8_t*)&sA[(mt * 16 + mrow) * 272 + k0 + quad * 8];
        #pragma unroll
        for (int nt = 0; nt < 4; ++nt)
            bb[nt] = *(const s16x8_t*)(W1T + (size_t)(64 * w + nt * 16 + mrow) * 256 + k0 + quad * 8);
        #pragma unroll
        for (int mt = 0; mt < 4; ++mt) {
            #pragma unroll
            for (int nt = 0; nt < 4; ++nt)
                acc[mt * 4 + nt] = __builtin_amdgcn_mfma_f32_16x16x32_bf16(
                    a[mt], bb[nt], acc[mt * 4 + nt], 0, 0, 0);
        }
    }
    __syncthreads();

    #pragma unroll
    for (int nt = 0; nt < 4; ++nt) {
        int col = 64 * w + nt * 16 + mrow;
        float bias = b1[col];
        #pragma unroll
        for (int mt = 0; mt < 4; ++mt) {
            f32x4_t v = acc[mt * 4 + nt];
            #pragma unroll
            for (int reg = 0; reg < 4; ++reg) {
                int row = mt * 16 + quad * 4 + reg;
                sA[row * 272 + col] = f2bf(fmaxf(v[reg] + bias, 0.f));
            }
        }
    }
    __syncthreads();

    #pragma unroll
    for (int i = 0; i < 16; ++i) acc[i] = (f32x4_t){0.f, 0.f, 0.f, 0.f};

    #pragma unroll
    for (int k0 = 0; k0 < 256; k0 += 32) {
        s16x8_t a[4], bb[4];
        #pragma unroll
        for (int mt = 0; mt < 4; ++mt)
            a[mt] = *(const s16x8_t*)&sA[(mt * 16 + mrow) * 272 + k0 + quad * 8];
        #pragma unroll
        for (int nt = 0; nt < 4; ++nt)
            bb[nt] = *(const s16x8_t*)(W2T + (size_t)(64 * w + nt * 16 + mrow) * 256 + k0 + quad * 8);
        #pragma unroll
        for (int mt = 0; mt < 4; ++mt) {
            #pragma unroll
            for (int nt = 0; nt < 4; ++nt)
                acc[mt * 4 + nt] = __builtin_amdgcn_mfma_f32_16x16x32_bf16(
                    a[mt], bb[nt], acc[mt * 4 + nt], 0, 0, 0);
        }
    }

    #pragma unroll
    for (int nt = 0; nt < 4; ++nt) {
        int col = 64 * w + nt * 16 + mrow;
        float bias = b2[col];
        #pragma unroll
        for (int mt = 0; mt < 4; ++mt) {
            f32x4_t v = acc[mt * 4 + nt];
            #pragma unroll
            for (int reg = 0; reg < 4; ++reg) {
                int row = blk * 64 + mt * 16 + quad * 4 + reg;
                Y[(size_t)row * 256 + col] = v[reg] + bias;
            }
        }
    }
}

// ---------------------------------------------------------------------------
// Kernel C: per-b fused K-build -> 20x linear-domain Sinkhorn -> score.
// Thread (r = t>>2, q = t&3) owns:
//   K  row chunk  K[r][64q..64q+63]   as 64 f32 registers
//   K^T col chunk K[64q..64q+63][r]   as 32 packed-bf16 uint registers
// __launch_bounds__(1024,4): 4 waves/EU -> 128-VGPR budget, no scratch spill.
// ru/rv padded to 68-float chunks -> conflict-free 4-address broadcast reads.
// ---------------------------------------------------------------------------
__global__ __launch_bounds__(1024, 4) void sink_kernel(
    const float* __restrict__ Tplan, const int* __restrict__ from_idx,
    const int* __restrict__ to_idx, const int* __restrict__ qsz,
    const int* __restrict__ csz, const float* __restrict__ qcf,
    float* __restrict__ out)
{
    const int b = blockIdx.x;
    const int t = threadIdx.x;
    const int r = t >> 2;   // row (row step) / col j (col step)
    const int q = t & 3;    // 64-wide chunk

    // overlay region: build {Tl | fq/tq/fc/tc} vs score {plan_s | cf_s}
    __shared__ __align__(16) char ovl[56320];
    __shared__ float ru_s[272], rv_s[272];   // padded: chunk q at q*68
    __shared__ float wsum[16];

    float* Tl = (float*)ovl;                 // 33*33 floats
    int* fq = (int*)(ovl + 4368);
    int* tq = (int*)(ovl + 5392);
    int* fc = (int*)(ovl + 6416);
    int* tc = (int*)(ovl + 7440);
    float* plan_s = (float*)ovl;             // [256][25] f32
    float* cf_s   = (float*)(ovl + 25600);   // [24][16 chunks * 20] f32, swizzled

    // --- phase 1 ---
    for (int i = t; i < 33 * 33; i += 1024) Tl[i] = 0.f;
    if (t < 256) {
        rv_s[PADIDX(t)] = 1.0f;
        int gq = 2 * b, gc = 2 * b + 1;
        int a = NMAXI, bb = NMAXI, c = NMAXI, d = NMAXI;
        if (t < EPG) {
            a  = from_idx[gq * EPG + t] - gq * NPG;
            bb = to_idx  [gq * EPG + t] - gq * NPG;
            c  = from_idx[gc * EPG + t] - gc * NPG;
            d  = to_idx  [gc * EPG + t] - gc * NPG;
        }
        fq[t] = a; tq[t] = bb; fc[t] = c; tc[t] = d;
    }
    __syncthreads();
    {
        int i = t >> 5, j = t & 31;
        Tl[i * 33 + j] = Tplan[((size_t)b << 10) + t];
    }
    __syncthreads();

    // --- build K row chunk (f32 registers) ---
    float K[64];
    {
        const float* T1 = &Tl[fq[r] * 33];
        const float* T2 = &Tl[tq[r] * 33];
        #pragma unroll
        for (int o = 0; o < 64; ++o) {
            int cidx = q * 64 + o;
            int f_ = fc[cidx], t_ = tc[cidx];
            float la = T1[f_] * T2[t_] + T1[t_] * T2[f_];
            K[o] = exp2f(la * L2E_OVER_T);
        }
    }
    // --- build K^T col chunk (packed bf16 registers) ---
    uint_t KTp[32];
    {
        int j = r;
        int f_ = fc[j], t_ = tc[j];
        #pragma unroll
        for (int oo = 0; oo < 8; ++oo) {
            #pragma unroll
            for (int p2 = 0; p2 < 4; ++p2) {
                int i0 = q * 64 + oo * 8 + p2 * 2;
                const float* A1 = &Tl[fq[i0] * 33];
                const float* A2 = &Tl[tq[i0] * 33];
                float la0 = A1[f_] * A2[t_] + A1[t_] * A2[f_];
                const float* B1 = &Tl[fq[i0 + 1] * 33];
                const float* B2 = &Tl[tq[i0 + 1] * 33];
                float la1 = B1[f_] * B2[t_] + B1[t_] * B2[f_];
                KTp[oo * 4 + p2] = (uint_t)f2bf(exp2f(la0 * L2E_OVER_T))
                                 | ((uint_t)f2bf(exp2f(la1 * L2E_OVER_T)) << 16);
            }
        }
    }

    // --- 20 Sinkhorn iterations, linear domain, all-register K ---
    const float4* rv4 = (const float4*)&rv_s[q * 68];
    const float4* ru4 = (const float4*)&ru_s[q * 68];

    for (int it = 0; it < 20; ++it) {
        // row step: U_r = sum_j K[r][j] * rv[j]
        float a0 = 0.f, a1 = 0.f, a2 = 0.f, a3 = 0.f;
        #pragma unroll
        for (int c4 = 0; c4 < 16; ++c4) {
            float4 v = rv4[c4];
            a0 += K[c4 * 4 + 0] * v.x;
            a1 += K[c4 * 4 + 1] * v.y;
            a2 += K[c4 * 4 + 2] * v.z;
            a3 += K[c4 * 4 + 3] * v.w;
        }
        float s = (a0 + a1) + (a2 + a3);
        s += __shfl_xor(s, 1);
        s += __shfl_xor(s, 2);
        if (q == 0) ru_s[PADIDX(r)] = frcp(s);
        __syncthreads();
        // col step: V_j = sum_i K[i][j] * ru[i]   (j = r, K^T from registers)
        a0 = a1 = a2 = a3 = 0.f;
        #pragma unroll
        for (int c8 = 0; c8 < 8; ++c8) {
            uint_t k0 = KTp[c8 * 4 + 0], k1 = KTp[c8 * 4 + 1];
            uint_t k2 = KTp[c8 * 4 + 2], k3 = KTp[c8 * 4 + 3];
            float4 u0 = ru4[c8 * 2 + 0];
            float4 u1 = ru4[c8 * 2 + 1];
            a0 += bflo(k0) * u0.x; a1 += bfhi(k0) * u0.y;
            a2 += bflo(k1) * u0.z; a3 += bfhi(k1) * u0.w;
            a0 += bflo(k2) * u1.x; a1 += bfhi(k2) * u1.y;
            a2 += bflo(k3) * u1.z; a3 += bfhi(k3) * u1.w;
        }
        s = (a0 + a1) + (a2 + a3);
        s += __shfl_xor(s, 1);
        s += __shfl_xor(s, 2);
        if (q == 0) rv_s[PADIDX(r)] = frcp(s);
        __syncthreads();
    }

    // --- score phase ---
    int nq = qsz[b]; if (nq > 24) nq = 24;
    int nc = csz[b]; if (nc > 24) nc = 24;

    if (q == 0) {   // plan[r][j] = K[r][j] * ru[r] * rv[j], j < 24
        float rr = ru_s[PADIDX(r)];
        #pragma unroll
        for (int j = 0; j < 24; ++j)
            plan_s[r * 25 + j] = K[j] * rr * rv_s[j];
    }
    if (t < 768) {  // cf rows -> swizzled LDS chunks of 16 floats @ stride 20
        int j = t >> 5, inner = t & 31;
        int c = inner * 8;
        const float* src = qcf + ((size_t)(2 * b + 1) * 24 + j) * 256 + c;
        float4 v0 = *(const float4*)(src);
        float4 v1 = *(const float4*)(src + 4);
        float* dst = cf_s + j * 320 + (c >> 4) * 20 + (c & 15);
        *(float4*)dst = v0;
        *(float4*)(dst + 4) = v1;
    }
    __syncthreads();

    // thread = 4 rows x 16 cols
    const int rg = t >> 4;
    const int r0 = rg * 4;
    const int m  = t & 15;

    float pc[64];
    #pragma unroll
    for (int i = 0; i < 64; ++i) pc[i] = 0.f;

    for (int j = 0; j < nc; ++j) {
        float p0 = plan_s[(r0 + 0) * 25 + j];
        float p1 = plan_s[(r0 + 1) * 25 + j];
        float p2 = plan_s[(r0 + 2) * 25 + j];
        float p3 = plan_s[(r0 + 3) * 25 + j];
        const float4* cfp = (const float4*)(cf_s + j * 320 + m * 20);
        #pragma unroll
        for (int k = 0; k < 4; ++k) {
            float4 cv = cfp[k];
            pc[ 0 + k * 4 + 0] += p0 * cv.x; pc[ 0 + k * 4 + 1] += p0 * cv.y;
            pc[ 0 + k * 4 + 2] += p0 * cv.z; pc[ 0 + k * 4 + 3] += p0 * cv.w;
            pc[16 + k * 4 + 0] += p1 * cv.x; pc[16 + k * 4 + 1] += p1 * cv.y;
            pc[16 + k * 4 + 2] += p1 * cv.z; pc[16 + k * 4 + 3] += p1 * cv.w;
            pc[32 + k * 4 + 0] += p2 * cv.x; pc[32 + k * 4 + 1] += p2 * cv.y;
            pc[32 + k * 4 + 2] += p2 * cv.z; pc[32 + k * 4 + 3] += p2 * cv.w;
            pc[48 + k * 4 + 0] += p3 * cv.x; pc[48 + k * 4 + 1] += p3 * cv.y;
            pc[48 + k * 4 + 2] += p3 * cv.z; pc[48 + k * 4 + 3] += p3 * cv.w;
        }
    }

    float ssum = 0.f;
    const float* qbase = qcf + (size_t)(2 * b) * 24 * 256;
    #pragma unroll
    for (int i = 0; i < 4; ++i) {
        int row = r0 + i;
        if (row < nq) {
            const float4* qp = (const float4*)(qbase + (size_t)row * 256 + m * 16);
            #pragma unroll
            for (int k = 0; k < 4; ++k) {
                float4 qv = qp[k];
                ssum += fmaxf(qv.x - pc[i * 16 + k * 4 + 0], 0.f);
                ssum += fmaxf(qv.y - pc[i * 16 + k * 4 + 1], 0.f);
                ssum += fmaxf(qv.z - pc[i * 16 + k * 4 + 2], 0.f);
                ssum += fmaxf(qv.w - pc[i * 16 + k * 4 + 3], 0.f);
            }
        } else {
            #pragma unroll
            for (int k = 0; k < 16; ++k) ssum += fmaxf(-pc[i * 16 + k], 0.f);
        }
    }
    ssum += __shfl_xor(ssum, 1);
    ssum += __shfl_xor(ssum, 2);
    ssum += __shfl_xor(ssum, 4);
    ssum += __shfl_xor(ssum, 8);
    ssum += __shfl_xor(ssum, 16);
    ssum += __shfl_xor(ssum, 32);
    if ((t & 63) == 0) wsum[t >> 6] = ssum;
    __syncthreads();
    if (t == 0) {
        float s = 0.f;
        #pragma unroll
        for (int i = 0; i < 16; ++i) s += wsum[i];
        out[b] = -s;
    }
}

// ---------------------------------------------------------------------------
extern "C" void kernel_launch(void* const* d_in, const int* in_sizes, int n_in,
                              void* d_out, int out_size, void* d_ws, size_t ws_size,
                              hipStream_t stream)
{
    const float* edge_feat = (const float*)d_in[0];
    const float* tplan     = (const float*)d_in[1];
    const float* W1        = (const float*)d_in[2];
    const float* b1        = (const float*)d_in[3];
    const float* W2        = (const float*)d_in[4];
    const float* b2        = (const float*)d_in[5];
    const int*   from_idx  = (const int*)d_in[6];
    const int*   to_idx    = (const int*)d_in[7];
    const int*   qsz       = (const int*)d_in[9];
    const int*   csz       = (const int*)d_in[10];
    float* out = (float*)d_out;

    // workspace: [0,128K) W1T bf16 | [128K,256K) W2T bf16 | [256K,+12.6MB) qcf f32
    char* ws = (char*)d_ws;
    ushort_t* W1T = (ushort_t*)ws;
    ushort_t* W2T = W1T + 65536;
    float* qcf = (float*)(ws + 262144);

    prep_w<<<64, 256, 0, stream>>>(W1, W2, W1T, W2T);
    mlp_kernel<<<192, 256, 0, stream>>>(edge_feat, W1T, W2T, b1, b2, qcf);
    sink_kernel<<<256, 1024, 0, stream>>>(tplan, from_idx, to_idx, qsz, csz, qcf, out);
}